// Round 1
// baseline (148.829 us; speedup 1.0000x reference)
//
#include <hip/hip_runtime.h>
#include <hip/hip_bf16.h>

#define S_LEN 4096
#define D_DIM 64
#define NBATCH 4

typedef unsigned short u16;
typedef unsigned int u32;
typedef __attribute__((ext_vector_type(8))) __bf16 bf16x8;
typedef __attribute__((ext_vector_type(4))) float f32x4;

__device__ __forceinline__ u16 f_to_bf16u(float f) {
    union { float f; u32 u; } x; x.f = f;
    u32 r = x.u + 0x7fffu + ((x.u >> 16) & 1u);   // RNE; inputs are finite
    return (u16)(r >> 16);
}

// ---------------------------------------------------------------------------
// QKV projection: out[r][o] = sum_d in[r][d]*W[o][d] + b[o]  (bf16 MFMA)
// p = blockIdx.y selects q/k/v. V is written TRANSPOSED: Vt[b][d][s].
// ---------------------------------------------------------------------------
__global__ __launch_bounds__(256, 2)
void proj_qkv_kernel(const float* __restrict__ q, const float* __restrict__ k,
                     const float* __restrict__ v,
                     const float* __restrict__ Wq, const float* __restrict__ bq,
                     const float* __restrict__ Wk, const float* __restrict__ bk,
                     const float* __restrict__ Wv, const float* __restrict__ bv,
                     u16* __restrict__ Qb, u16* __restrict__ Kb, u16* __restrict__ Vt)
{
    __shared__ __align__(16) u16 vt[64 * 72];

    const int p = blockIdx.y;
    const float* inp  = (p == 0) ? q  : (p == 1) ? k  : v;
    const float* W    = (p == 0) ? Wq : (p == 1) ? Wk : Wv;
    const float* bias = (p == 0) ? bq : (p == 1) ? bk : bv;

    const int tid  = threadIdx.x;
    const int wid  = tid >> 6;
    const int lane = tid & 63;
    const int ln   = lane & 15;
    const int qd   = lane >> 4;
    const int row0 = blockIdx.x * 64;
    const int r0w  = row0 + wid * 16;

    bf16x8 afrag[2];
#pragma unroll
    for (int c = 0; c < 2; ++c) {
        const float* src = inp + (r0w + ln) * 64 + c * 32 + qd * 8;
        float4 f0 = *(const float4*)src;
        float4 f1 = *(const float4*)(src + 4);
        bf16x8 a;
        a[0] = (__bf16)f0.x; a[1] = (__bf16)f0.y; a[2] = (__bf16)f0.z; a[3] = (__bf16)f0.w;
        a[4] = (__bf16)f1.x; a[5] = (__bf16)f1.y; a[6] = (__bf16)f1.z; a[7] = (__bf16)f1.w;
        afrag[c] = a;
    }

    bf16x8 bfrag[4][2];
    float  bcol[4];
#pragma unroll
    for (int nb = 0; nb < 4; ++nb) {
        bcol[nb] = bias[nb * 16 + ln];
#pragma unroll
        for (int c = 0; c < 2; ++c) {
            const float* src = W + (nb * 16 + ln) * 64 + c * 32 + qd * 8;
            float4 f0 = *(const float4*)src;
            float4 f1 = *(const float4*)(src + 4);
            bf16x8 b;
            b[0] = (__bf16)f0.x; b[1] = (__bf16)f0.y; b[2] = (__bf16)f0.z; b[3] = (__bf16)f0.w;
            b[4] = (__bf16)f1.x; b[5] = (__bf16)f1.y; b[6] = (__bf16)f1.z; b[7] = (__bf16)f1.w;
            bfrag[nb][c] = b;
        }
    }

    f32x4 acc[4];
#pragma unroll
    for (int nb = 0; nb < 4; ++nb) acc[nb] = (f32x4){0.f, 0.f, 0.f, 0.f};
#pragma unroll
    for (int c = 0; c < 2; ++c)
#pragma unroll
        for (int nb = 0; nb < 4; ++nb)
            acc[nb] = __builtin_amdgcn_mfma_f32_16x16x32_bf16(afrag[c], bfrag[nb][c], acc[nb], 0, 0, 0);

    if (p < 2) {
        u16* dst = (p == 0) ? Qb : Kb;
#pragma unroll
        for (int nb = 0; nb < 4; ++nb)
#pragma unroll
            for (int r = 0; r < 4; ++r) {
                int row = r0w + qd * 4 + r;
                dst[row * 64 + nb * 16 + ln] = f_to_bf16u(acc[nb][r] + bcol[nb]);
            }
    } else {
        // transpose through LDS, write Vt[b][d][s] coalesced
#pragma unroll
        for (int nb = 0; nb < 4; ++nb)
#pragma unroll
            for (int r = 0; r < 4; ++r)
                vt[(wid * 16 + qd * 4 + r) * 72 + nb * 16 + ln] = f_to_bf16u(acc[nb][r] + bcol[nb]);
        __syncthreads();
        const int d  = tid >> 2;
        const int sc = tid & 3;
        const int b  = row0 >> 12;
        const int sb = row0 & 4095;
        __align__(16) u16 tmp[16];
#pragma unroll
        for (int i = 0; i < 16; ++i) tmp[i] = vt[(sc * 16 + i) * 72 + d];
        u16* dstp = Vt + (size_t)b * (64 * S_LEN) + d * S_LEN + sb + sc * 16;
        *(uint4*)(dstp)     = *(const uint4*)(tmp);
        *(uint4*)(dstp + 8) = *(const uint4*)(tmp + 8);
    }
}

// ---------------------------------------------------------------------------
// Flash attention with ANTI-causal mask (col >= row allowed).
// BM=32 (2 row-groups of 16), BN=128 (2 col-groups of 64), 4 waves.
// Each wave keeps private (m,l,O); col-groups combined in the epilogue.
// ---------------------------------------------------------------------------
__global__ __launch_bounds__(256, 2)
void flash_kernel(const u16* __restrict__ Qb, const u16* __restrict__ Kb,
                  const u16* __restrict__ Vt, u16* __restrict__ Ob)
{
    __shared__ __align__(16) u16  lds_k[128 * 72];   // K rows, pad 64->72
    __shared__ __align__(16) u16  lds_v[64 * 136];   // V^T rows (d-major), pad 128->136
    __shared__ __align__(16) u16  lds_p[4 * 16 * 72];// per-wave P buffer
    __shared__ float lds_c[2 * 1056];                // per row-group: O(16x64) + m(16) + l(16)

    const int tid  = threadIdx.x;
    const int wid  = tid >> 6;
    const int lane = tid & 63;
    const int ln   = lane & 15;
    const int qd   = lane >> 4;
    const int wr   = wid & 1;    // row-group
    const int wc   = wid >> 1;   // col-group

    // balanced tile mapping: heavy (low i0) tiles first, complementary pairing
    const int bid   = blockIdx.x;
    const int half  = bid >> 8;
    const int idx   = bid & 255;
    const int batch = idx & 3;
    const int tb    = (half == 0) ? (idx >> 2) : (127 - (idx >> 2));
    const int i0    = tb * 32;
    const int j_start = i0 & ~127;

    const int qr0 = i0 + wr * 16;
    const u16* qbase = Qb + ((size_t)batch * S_LEN + qr0 + ln) * 64;
    bf16x8 qfrag[2];
    qfrag[0] = *(const bf16x8*)(qbase + qd * 8);
    qfrag[1] = *(const bf16x8*)(qbase + 32 + qd * 8);

    f32x4 oacc[4];
#pragma unroll
    for (int nb = 0; nb < 4; ++nb) oacc[nb] = (f32x4){0.f, 0.f, 0.f, 0.f};
    float m_r[4], l_r[4];
#pragma unroll
    for (int r = 0; r < 4; ++r) { m_r[r] = -1e30f; l_r[r] = 0.f; }

    const float SCL = 0.125f * 1.44269504f;   // scale * log2(e)

    for (int j0 = j_start; j0 < S_LEN; j0 += 128) {
        __syncthreads();
        // stage K tile: 128 rows x 64 bf16 (16 KB)
        {
            const uint4* gk = (const uint4*)(Kb + ((size_t)batch * S_LEN + j0) * 64);
#pragma unroll
            for (int it = 0; it < 4; ++it) {
                int id2 = it * 256 + tid;
                int row = id2 >> 3, c8 = id2 & 7;
                uint4 val = gk[id2];
                *(uint4*)(&lds_k[row * 72 + c8 * 8]) = val;
            }
            const u16* gvb = Vt + (size_t)batch * (64 * S_LEN) + j0;
#pragma unroll
            for (int it = 0; it < 4; ++it) {
                int id2 = it * 256 + tid;
                int d = id2 >> 4, c16 = id2 & 15;
                uint4 val = *(const uint4*)(gvb + d * S_LEN + c16 * 8);
                *(uint4*)(&lds_v[d * 136 + c16 * 8]) = val;
            }
        }
        __syncthreads();

        // S = Q K^T for this wave's 16x64 slice
        f32x4 sacc[4];
#pragma unroll
        for (int nb = 0; nb < 4; ++nb) sacc[nb] = (f32x4){0.f, 0.f, 0.f, 0.f};
#pragma unroll
        for (int c = 0; c < 2; ++c)
#pragma unroll
            for (int nb = 0; nb < 4; ++nb) {
                bf16x8 bk = *(const bf16x8*)(&lds_k[(wc * 64 + nb * 16 + ln) * 72 + c * 32 + qd * 8]);
                sacc[nb] = __builtin_amdgcn_mfma_f32_16x16x32_bf16(qfrag[c], bk, sacc[nb], 0, 0, 0);
            }

        float sl[4][4];
#pragma unroll
        for (int nb = 0; nb < 4; ++nb)
#pragma unroll
            for (int r = 0; r < 4; ++r) sl[nb][r] = sacc[nb][r] * SCL;

        if (j0 == j_start) {   // only the first K-block can be masked
            int colb = j0 + wc * 64 + ln;
            int rowb = qr0 + qd * 4;
#pragma unroll
            for (int nb = 0; nb < 4; ++nb)
#pragma unroll
                for (int r = 0; r < 4; ++r)
                    if (colb + nb * 16 < rowb + r) sl[nb][r] = -1e30f;
        }

        float pnew[4][4], alpha[4];
#pragma unroll
        for (int r = 0; r < 4; ++r) {
            float vmx = fmaxf(fmaxf(sl[0][r], sl[1][r]), fmaxf(sl[2][r], sl[3][r]));
            vmx = fmaxf(vmx, __shfl_xor(vmx, 1));
            vmx = fmaxf(vmx, __shfl_xor(vmx, 2));
            vmx = fmaxf(vmx, __shfl_xor(vmx, 4));
            vmx = fmaxf(vmx, __shfl_xor(vmx, 8));
            float mn = fmaxf(m_r[r], vmx);
            alpha[r] = exp2f(m_r[r] - mn);
            float rs = 0.f;
#pragma unroll
            for (int nb = 0; nb < 4; ++nb) {
                float pv = exp2f(sl[nb][r] - mn);
                pnew[nb][r] = pv;
                rs += pv;
            }
            rs += __shfl_xor(rs, 1);
            rs += __shfl_xor(rs, 2);
            rs += __shfl_xor(rs, 4);
            rs += __shfl_xor(rs, 8);
            l_r[r] = l_r[r] * alpha[r] + rs;
            m_r[r] = mn;
        }
#pragma unroll
        for (int nb = 0; nb < 4; ++nb)
#pragma unroll
            for (int r = 0; r < 4; ++r) oacc[nb][r] *= alpha[r];

        // P: C-layout -> LDS -> A-layout (m120-verified transform)
        u16* pb = lds_p + wid * (16 * 72);
#pragma unroll
        for (int nb = 0; nb < 4; ++nb)
#pragma unroll
            for (int r = 0; r < 4; ++r)
                pb[(qd * 4 + r) * 72 + nb * 16 + ln] = f_to_bf16u(pnew[nb][r]);

#pragma unroll
        for (int c = 0; c < 2; ++c) {
            bf16x8 pa = *(const bf16x8*)(&pb[ln * 72 + c * 32 + qd * 8]);
#pragma unroll
            for (int onb = 0; onb < 4; ++onb) {
                bf16x8 vb = *(const bf16x8*)(&lds_v[(onb * 16 + ln) * 136 + wc * 64 + c * 32 + qd * 8]);
                oacc[onb] = __builtin_amdgcn_mfma_f32_16x16x32_bf16(pa, vb, oacc[onb], 0, 0, 0);
            }
        }
    }

    // combine the two col-groups per row-group, normalize, store bf16 O
    __syncthreads();
    float* cmb = lds_c + wr * 1056;
    if (wc == 1) {
#pragma unroll
        for (int r = 0; r < 4; ++r) {
            int rowc = qd * 4 + r;
            if (ln == 0) { cmb[1024 + rowc] = m_r[r]; cmb[1040 + rowc] = l_r[r]; }
#pragma unroll
            for (int onb = 0; onb < 4; ++onb)
                cmb[rowc * 64 + onb * 16 + ln] = oacc[onb][r];
        }
    }
    __syncthreads();
    if (wc == 0) {
        u16* obase = Ob + ((size_t)batch * S_LEN + qr0) * 64;
#pragma unroll
        for (int r = 0; r < 4; ++r) {
            int rowc = qd * 4 + r;
            float m1 = cmb[1024 + rowc], l1 = cmb[1040 + rowc];
            float ms = fmaxf(m_r[r], m1);
            float e0 = exp2f(m_r[r] - ms);
            float e1 = exp2f(m1 - ms);
            float inv = 1.0f / (l_r[r] * e0 + l1 * e1);
#pragma unroll
            for (int onb = 0; onb < 4; ++onb) {
                float o = (oacc[onb][r] * e0 + cmb[rowc * 64 + onb * 16 + ln] * e1) * inv;
                obase[rowc * 64 + onb * 16 + ln] = f_to_bf16u(o);
            }
        }
    }
}

// ---------------------------------------------------------------------------
// Output projection: out = O @ Wp^T + bp  (bf16 A, fp32 result)
// ---------------------------------------------------------------------------
__global__ __launch_bounds__(256, 2)
void proj_out_kernel(const u16* __restrict__ Ob, const float* __restrict__ Wp,
                     const float* __restrict__ bp, float* __restrict__ out)
{
    const int tid  = threadIdx.x;
    const int wid  = tid >> 6;
    const int lane = tid & 63;
    const int ln   = lane & 15;
    const int qd   = lane >> 4;
    const int r0w  = blockIdx.x * 64 + wid * 16;

    bf16x8 afrag[2];
#pragma unroll
    for (int c = 0; c < 2; ++c)
        afrag[c] = *(const bf16x8*)(Ob + (size_t)(r0w + ln) * 64 + c * 32 + qd * 8);

    bf16x8 bfrag[4][2];
    float  bcol[4];
#pragma unroll
    for (int nb = 0; nb < 4; ++nb) {
        bcol[nb] = bp[nb * 16 + ln];
#pragma unroll
        for (int c = 0; c < 2; ++c) {
            const float* src = Wp + (nb * 16 + ln) * 64 + c * 32 + qd * 8;
            float4 f0 = *(const float4*)src;
            float4 f1 = *(const float4*)(src + 4);
            bf16x8 b;
            b[0] = (__bf16)f0.x; b[1] = (__bf16)f0.y; b[2] = (__bf16)f0.z; b[3] = (__bf16)f0.w;
            b[4] = (__bf16)f1.x; b[5] = (__bf16)f1.y; b[6] = (__bf16)f1.z; b[7] = (__bf16)f1.w;
            bfrag[nb][c] = b;
        }
    }

    f32x4 acc[4];
#pragma unroll
    for (int nb = 0; nb < 4; ++nb) acc[nb] = (f32x4){0.f, 0.f, 0.f, 0.f};
#pragma unroll
    for (int c = 0; c < 2; ++c)
#pragma unroll
        for (int nb = 0; nb < 4; ++nb)
            acc[nb] = __builtin_amdgcn_mfma_f32_16x16x32_bf16(afrag[c], bfrag[nb][c], acc[nb], 0, 0, 0);

#pragma unroll
    for (int nb = 0; nb < 4; ++nb)
#pragma unroll
        for (int r = 0; r < 4; ++r) {
            int row = r0w + qd * 4 + r;
            out[(size_t)row * 64 + nb * 16 + ln] = acc[nb][r] + bcol[nb];
        }
}

extern "C" void kernel_launch(void* const* d_in, const int* in_sizes, int n_in,
                              void* d_out, int out_size, void* d_ws, size_t ws_size,
                              hipStream_t stream) {
    const float* q  = (const float*)d_in[0];
    const float* k  = (const float*)d_in[1];
    const float* v  = (const float*)d_in[2];
    const float* Wq = (const float*)d_in[3];
    const float* bq = (const float*)d_in[4];
    const float* Wk = (const float*)d_in[5];
    const float* bk = (const float*)d_in[6];
    const float* Wv = (const float*)d_in[7];
    const float* bv = (const float*)d_in[8];
    const float* Wp = (const float*)d_in[9];
    const float* bp = (const float*)d_in[10];
    float* out = (float*)d_out;

    const size_t NTOK = (size_t)NBATCH * S_LEN * D_DIM;  // 1,048,576
    u16* Qb = (u16*)d_ws;          // 2 MB each; total 8 MB of workspace
    u16* Kb = Qb + NTOK;
    u16* Vt = Kb + NTOK;           // transposed V: [b][d][s]
    u16* Ob = Vt + NTOK;

    proj_qkv_kernel<<<dim3(256, 3), 256, 0, stream>>>(q, k, v, Wq, bq, Wk, bk, Wv, bv, Qb, Kb, Vt);
    flash_kernel<<<512, 256, 0, stream>>>(Qb, Kb, Vt, Ob);
    proj_out_kernel<<<256, 256, 0, stream>>>(Ob, Wp, bp, out);
}